// Round 1
// baseline (2730.477 us; speedup 1.0000x reference)
//
#include <hip/hip_runtime.h>
#include <hip/hip_bf16.h>

typedef __bf16 bf16x8 __attribute__((ext_vector_type(8)));
typedef float  f32x4  __attribute__((ext_vector_type(4)));

__device__ __forceinline__ unsigned short f2bf(float f) {
    union { float f; unsigned int u; } v; v.f = f;
    unsigned int r = v.u + 0x7fffu + ((v.u >> 16) & 1u);
    return (unsigned short)(r >> 16);
}
__device__ __forceinline__ float bf2f(unsigned short h) {
    union { unsigned int u; float f; } v; v.u = ((unsigned int)h) << 16;
    return v.f;
}

// ---------------- cast fp32 -> bf16 (flat) ----------------
__global__ void k_cast(const float* __restrict__ in, unsigned short* __restrict__ out, int n) {
    int i = (blockIdx.x * blockDim.x + threadIdx.x) * 4;
    if (i + 3 < n) {
        float4 v = *reinterpret_cast<const float4*>(in + i);
        ushort4 o;
        o.x = f2bf(v.x); o.y = f2bf(v.y); o.z = f2bf(v.z); o.w = f2bf(v.w);
        *reinterpret_cast<ushort4*>(out + i) = o;
    }
}

// ---------------- transpose + cast: in [K][N] f32 -> out [N][K] bf16 ----------------
__global__ void k_transpose_cast(const float* __restrict__ in, unsigned short* __restrict__ out,
                                 int K, int N) {
    __shared__ float tile[32][33];
    int n0 = blockIdx.x * 32, k0 = blockIdx.y * 32;
    int tx = threadIdx.x, ty = threadIdx.y; // block (32,8)
    for (int i = 0; i < 4; ++i)
        tile[ty + i * 8][tx] = in[(size_t)(k0 + ty + i * 8) * N + n0 + tx];
    __syncthreads();
    for (int i = 0; i < 4; ++i)
        out[(size_t)(n0 + ty + i * 8) * K + k0 + tx] = f2bf(tile[tx][ty + i * 8]);
}

// ---------------- fill float ----------------
__global__ void k_fill(float* __restrict__ p, float v, int n) {
    int i = blockIdx.x * blockDim.x + threadIdx.x;
    if (i < n) p[i] = v;
}

// ---------------- bf16 MFMA GEMM: out = A[M,K] * Bt[N,K]^T + bias ----------------
// mode 0: out bf16 row-major [M,N]
// mode 1: out bf16 scattered to [B,H,T,D] (row=b*T+t, col=h*D+d), val=(acc+bias)*scale
// mode 2: out fp32 row-major [M,N]
__global__ __launch_bounds__(256) void k_gemm(
    const unsigned short* __restrict__ A, int lda,
    const unsigned short* __restrict__ Bt,
    const float* __restrict__ bias,
    void* __restrict__ out,
    int M, int N, int K, int mode, float scale)
{
    __shared__ unsigned short As[128 * 40];
    __shared__ unsigned short Bs[128 * 40];
    int tid  = threadIdx.x;
    int lane = tid & 63, wv = tid >> 6;
    int quad = lane >> 4, l16 = lane & 15;
    int bm = blockIdx.y * 128, bn = blockIdx.x * 128;
    int wm = (wv >> 1) * 64,  wn = (wv & 1) * 64;

    f32x4 acc[4][4] = {};

    for (int k0 = 0; k0 < K; k0 += 32) {
        for (int s = 0; s < 2; ++s) {
            int vi = s * 256 + tid;      // 0..511
            int r  = vi >> 2, c8 = (vi & 3) * 8;
            *reinterpret_cast<uint4*>(&As[r * 40 + c8]) =
                *reinterpret_cast<const uint4*>(&A[(size_t)(bm + r) * lda + k0 + c8]);
            *reinterpret_cast<uint4*>(&Bs[r * 40 + c8]) =
                *reinterpret_cast<const uint4*>(&Bt[(size_t)(bn + r) * K + k0 + c8]);
        }
        __syncthreads();
        bf16x8 af[4], bfv[4];
        for (int mi = 0; mi < 4; ++mi)
            af[mi] = *reinterpret_cast<const bf16x8*>(&As[(wm + mi * 16 + l16) * 40 + quad * 8]);
        for (int ni = 0; ni < 4; ++ni)
            bfv[ni] = *reinterpret_cast<const bf16x8*>(&Bs[(wn + ni * 16 + l16) * 40 + quad * 8]);
        for (int mi = 0; mi < 4; ++mi)
            for (int ni = 0; ni < 4; ++ni)
                acc[mi][ni] = __builtin_amdgcn_mfma_f32_16x16x32_bf16(af[mi], bfv[ni], acc[mi][ni], 0, 0, 0);
        __syncthreads();
    }

    for (int mi = 0; mi < 4; ++mi) {
        for (int ni = 0; ni < 4; ++ni) {
            int col = bn + wn + ni * 16 + l16;
            float bsv = bias[col];
            for (int ri = 0; ri < 4; ++ri) {
                int row = bm + wm + mi * 16 + quad * 4 + ri;
                float val = (acc[mi][ni][ri] + bsv) * scale;
                if (mode == 0) {
                    reinterpret_cast<unsigned short*>(out)[(size_t)row * N + col] = f2bf(val);
                } else if (mode == 1) {
                    int b = row >> 12, t = row & 4095;
                    int h = col >> 6,  d = col & 63;
                    size_t idx = (((size_t)b * 16 + h) * 4096 + t) * 64 + d;
                    reinterpret_cast<unsigned short*>(out)[idx] = f2bf(val);
                } else {
                    reinterpret_cast<float*>(out)[(size_t)row * N + col] = val;
                }
            }
        }
    }
}

// ---------------- dilated attention, one branch ----------------
// grid: (8 qtiles, n_seg, B*H), block 256. eff=512, D=64.
__global__ __launch_bounds__(256) void k_attn(
    const unsigned short* __restrict__ qg,
    const unsigned short* __restrict__ kg,
    const unsigned short* __restrict__ vg,
    unsigned short* __restrict__ Obr,
    float* __restrict__ Lbr,
    int w, int r, int branch)
{
    __shared__ unsigned short Qs[64 * 72];
    __shared__ unsigned short Ks[64 * 72];
    __shared__ unsigned short Vs[64 * 72];   // transposed: [d][kcol]
    __shared__ float          Ss[64 * 68];
    __shared__ unsigned short Ps[64 * 72];
    __shared__ float m_s[64], l_s[64], alpha_s[64];

    int tid  = threadIdx.x;
    int lane = tid & 63, wv = tid >> 6;
    int quad = lane >> 4, l16 = lane & 15;
    int qt  = blockIdx.x;
    int seg = blockIdx.y;
    int bh  = blockIdx.z;
    int h   = bh & 15;
    int off = h & (r - 1);   // h % r, r power of 2
    const size_t headoff = (size_t)bh * 4096 * 64;
    const unsigned short* qh = qg + headoff;
    const unsigned short* kh = kg + headoff;
    const unsigned short* vh = vg + headoff;

    // load Q tile (64 rows x 64 d)
    for (int s = 0; s < 2; ++s) {
        int vi  = s * 256 + tid;
        int row = vi >> 3, c8 = (vi & 7) * 8;
        int pos = seg * w + off + (qt * 64 + row) * r;
        *reinterpret_cast<uint4*>(&Qs[row * 72 + c8]) =
            *reinterpret_cast<const uint4*>(&qh[(size_t)pos * 64 + c8]);
    }
    if (tid < 64) { m_s[tid] = -1e30f; l_s[tid] = 0.f; }

    f32x4 acc[4] = {};
    int base_m = wv * 16;

    for (int jt = 0; jt <= qt; ++jt) {
        __syncthreads();  // prev-iter reads done before overwriting K/V; also covers Q/m/l init
        for (int s = 0; s < 2; ++s) {
            int vi  = s * 256 + tid;
            int row = vi >> 3, c8 = (vi & 7) * 8;
            int pos = seg * w + off + (jt * 64 + row) * r;
            *reinterpret_cast<uint4*>(&Ks[row * 72 + c8]) =
                *reinterpret_cast<const uint4*>(&kh[(size_t)pos * 64 + c8]);
            uint4 vv = *reinterpret_cast<const uint4*>(&vh[(size_t)pos * 64 + c8]);
            const unsigned short* pv = reinterpret_cast<const unsigned short*>(&vv);
            for (int u = 0; u < 8; ++u)
                Vs[(c8 + u) * 72 + row] = pv[u];
        }
        __syncthreads();

        // S = Q K^T, masked, into LDS
        for (int nt = 0; nt < 4; ++nt) {
            f32x4 s4 = {};
            for (int ks = 0; ks < 2; ++ks) {
                bf16x8 a = *reinterpret_cast<const bf16x8*>(&Qs[(base_m + l16) * 72 + ks * 32 + quad * 8]);
                bf16x8 b = *reinterpret_cast<const bf16x8*>(&Ks[(nt * 16 + l16) * 72 + ks * 32 + quad * 8]);
                s4 = __builtin_amdgcn_mfma_f32_16x16x32_bf16(a, b, s4, 0, 0, 0);
            }
            for (int ri = 0; ri < 4; ++ri) {
                int row  = base_m + quad * 4 + ri;
                int colk = nt * 16 + l16;
                int qi = qt * 64 + row, kj = jt * 64 + colk;
                Ss[row * 68 + colk] = (kj <= qi) ? s4[ri] : -1e30f;
            }
        }
        __syncthreads();

        // online softmax (per-row)
        if (tid < 64) {
            int row = tid;
            float mx = -1e30f;
            for (int c = 0; c < 64; ++c) mx = fmaxf(mx, Ss[row * 68 + c]);
            float mold = m_s[row];
            float mnew = fmaxf(mold, mx);
            float alpha = __expf(mold - mnew);
            float sum = 0.f;
            for (int c = 0; c < 64; ++c) {
                float p = __expf(Ss[row * 68 + c] - mnew);
                Ps[row * 72 + c] = f2bf(p);
                sum += p;
            }
            l_s[row] = l_s[row] * alpha + sum;
            m_s[row] = mnew;
            alpha_s[row] = alpha;
        }
        __syncthreads();

        // O = O*alpha + P V
        float al[4];
        for (int ri = 0; ri < 4; ++ri) al[ri] = alpha_s[base_m + quad * 4 + ri];
        for (int dt = 0; dt < 4; ++dt) {
            f32x4 a4 = acc[dt];
            for (int ri = 0; ri < 4; ++ri) a4[ri] *= al[ri];
            for (int ks = 0; ks < 2; ++ks) {
                bf16x8 a = *reinterpret_cast<const bf16x8*>(&Ps[(base_m + l16) * 72 + ks * 32 + quad * 8]);
                bf16x8 b = *reinterpret_cast<const bf16x8*>(&Vs[(dt * 16 + l16) * 72 + ks * 32 + quad * 8]);
                a4 = __builtin_amdgcn_mfma_f32_16x16x32_bf16(a, b, a4, 0, 0, 0);
            }
            acc[dt] = a4;
        }
    }
    __syncthreads();

    size_t obase = ((size_t)(branch * 32 + bh)) * 4096 * 64;
    for (int dt = 0; dt < 4; ++dt) {
        for (int ri = 0; ri < 4; ++ri) {
            int row = base_m + quad * 4 + ri;
            int pos = seg * w + off + (qt * 64 + row) * r;
            int d   = dt * 16 + l16;
            Obr[obase + (size_t)pos * 64 + d] = f2bf(acc[dt][ri] / l_s[row]);
        }
    }
    if (tid < 64) {
        int row = tid;
        int pos = seg * w + off + (qt * 64 + row) * r;
        Lbr[(size_t)(branch * 32 + bh) * 4096 + pos] = m_s[row] + __logf(l_s[row]);
    }
}

// ---------------- combine branches via LSE weights ----------------
__global__ void k_combine(const unsigned short* __restrict__ Obr,
                          const float* __restrict__ Lbr,
                          unsigned short* __restrict__ yb)
{
    int g   = blockIdx.x * blockDim.x + threadIdx.x; // 131072 rows * 8 parts
    int row = g >> 3;
    int d0  = (g & 7) * 8;
    const int R = 2 * 16 * 4096;
    float L0 = Lbr[row], L1 = Lbr[R + row], L2 = Lbr[2 * R + row];
    float m  = fmaxf(L0, fmaxf(L1, L2));
    float w0 = __expf(L0 - m), w1 = __expf(L1 - m), w2 = __expf(L2 - m);
    float inv = 1.f / (w0 + w1 + w2);
    int bh = row >> 12, t = row & 4095;
    int b = bh >> 4, h = bh & 15;
    uint4 v0 = *reinterpret_cast<const uint4*>(&Obr[(size_t)row * 64 + d0]);
    uint4 v1 = *reinterpret_cast<const uint4*>(&Obr[(size_t)R * 64 + (size_t)row * 64 + d0]);
    uint4 v2 = *reinterpret_cast<const uint4*>(&Obr[(size_t)2 * R * 64 + (size_t)row * 64 + d0]);
    const unsigned short* p0 = reinterpret_cast<const unsigned short*>(&v0);
    const unsigned short* p1 = reinterpret_cast<const unsigned short*>(&v1);
    const unsigned short* p2 = reinterpret_cast<const unsigned short*>(&v2);
    unsigned short o[8];
    for (int u = 0; u < 8; ++u)
        o[u] = f2bf((w0 * bf2f(p0[u]) + w1 * bf2f(p1[u]) + w2 * bf2f(p2[u])) * inv);
    size_t yidx = (((size_t)b * 4096 + t) * 1024) + (size_t)h * 64 + d0;
    *reinterpret_cast<uint4*>(&yb[yidx]) = *reinterpret_cast<const uint4*>(o);
}

extern "C" void kernel_launch(void* const* d_in, const int* in_sizes, int n_in,
                              void* d_out, int out_size, void* d_ws, size_t ws_size,
                              hipStream_t stream)
{
    const float* x        = (const float*)d_in[0];
    const float* c_attn_w = (const float*)d_in[1];
    const float* c_attn_b = (const float*)d_in[2];
    const float* q_w      = (const float*)d_in[3];
    const float* q_b      = (const float*)d_in[4];
    const float* k_w      = (const float*)d_in[5];
    const float* k_b      = (const float*)d_in[6];
    const float* v_w      = (const float*)d_in[7];
    const float* v_b      = (const float*)d_in[8];
    const float* o_w      = (const float*)d_in[9];
    const float* o_b      = (const float*)d_in[10];

    char* ws = (char*)d_ws;
    size_t off = 0;
    auto alloc = [&](size_t bytes) -> char* {
        char* p = ws + off; off += (bytes + 255) & ~(size_t)255; return p;
    };
    unsigned short* xb    = (unsigned short*)alloc(8192ull * 1024 * 2);
    unsigned short* wqkvT = (unsigned short*)alloc(3072ull * 1024 * 2);
    unsigned short* wqT   = (unsigned short*)alloc(1024ull * 1024 * 2);
    unsigned short* wkT   = (unsigned short*)alloc(1024ull * 1024 * 2);
    unsigned short* wvT   = (unsigned short*)alloc(1024ull * 1024 * 2);
    unsigned short* woT   = (unsigned short*)alloc(1024ull * 1024 * 2);
    unsigned short* qkvb  = (unsigned short*)alloc(8192ull * 3072 * 2);
    unsigned short* qb    = (unsigned short*)alloc(2ull * 16 * 4096 * 64 * 2);
    unsigned short* kb    = (unsigned short*)alloc(2ull * 16 * 4096 * 64 * 2);
    unsigned short* vb    = (unsigned short*)alloc(2ull * 16 * 4096 * 64 * 2);
    unsigned short* Obr   = (unsigned short*)alloc(3ull * 2 * 16 * 4096 * 64 * 2);
    float*          Lbr   = (float*)alloc(3ull * 2 * 16 * 4096 * 4);
    unsigned short* yb    = xb;   // alias: x no longer needed after GEMM1

    // 1. cast x to bf16
    k_cast<<<(8192 * 1024) / 1024, 256, 0, stream>>>(x, xb, 8192 * 1024);
    // 2. transpose-cast weights to [N][K] bf16
    k_transpose_cast<<<dim3(3072 / 32, 1024 / 32), dim3(32, 8), 0, stream>>>(c_attn_w, wqkvT, 1024, 3072);
    k_transpose_cast<<<dim3(32, 32), dim3(32, 8), 0, stream>>>(q_w, wqT, 1024, 1024);
    k_transpose_cast<<<dim3(32, 32), dim3(32, 8), 0, stream>>>(k_w, wkT, 1024, 1024);
    k_transpose_cast<<<dim3(32, 32), dim3(32, 8), 0, stream>>>(v_w, wvT, 1024, 1024);
    k_transpose_cast<<<dim3(32, 32), dim3(32, 8), 0, stream>>>(o_w, woT, 1024, 1024);
    // 3. qkv = x @ c_attn_w + b
    k_gemm<<<dim3(24, 64), 256, 0, stream>>>(xb, 1024, wqkvT, c_attn_b, qkvb, 8192, 3072, 1024, 0, 1.f);
    // 4. q/k/v projections -> [B,H,T,D] bf16 (q scaled by D^-0.5)
    k_gemm<<<dim3(8, 64), 256, 0, stream>>>(qkvb + 0,    3072, wqT, q_b, qb, 8192, 1024, 1024, 1, 0.125f);
    k_gemm<<<dim3(8, 64), 256, 0, stream>>>(qkvb + 1024, 3072, wkT, k_b, kb, 8192, 1024, 1024, 1, 1.f);
    k_gemm<<<dim3(8, 64), 256, 0, stream>>>(qkvb + 2048, 3072, wvT, v_b, vb, 8192, 1024, 1024, 1, 1.f);
    // 5. init Lbr to -1e30 (uncovered positions must have zero combine weight)
    k_fill<<<(3 * 131072) / 256, 256, 0, stream>>>(Lbr, -1e30f, 3 * 131072);
    // 6. attention branches: (w,r) = (512,1),(1024,2),(2048,4)
    k_attn<<<dim3(8, 8, 32), 256, 0, stream>>>(qb, kb, vb, Obr, Lbr, 512, 1, 0);
    k_attn<<<dim3(8, 4, 32), 256, 0, stream>>>(qb, kb, vb, Obr, Lbr, 1024, 2, 1);
    k_attn<<<dim3(8, 2, 32), 256, 0, stream>>>(qb, kb, vb, Obr, Lbr, 2048, 4, 2);
    // 7. combine branches -> y [B,T,C] bf16
    k_combine<<<4096, 256, 0, stream>>>(Obr, Lbr, yb);
    // 8. out = y @ o_w + o_b (fp32)
    k_gemm<<<dim3(8, 64), 256, 0, stream>>>(yb, 1024, woT, o_b, d_out, 8192, 1024, 1024, 2, 1.f);
}

// Round 2
// 530.758 us; speedup vs baseline: 5.1445x; 5.1445x over previous
//
#include <hip/hip_runtime.h>
#include <hip/hip_bf16.h>

typedef __bf16 bf16x8 __attribute__((ext_vector_type(8)));
typedef float  f32x4  __attribute__((ext_vector_type(4)));

__device__ __forceinline__ unsigned short f2bf(float f) {
    union { float f; unsigned int u; } v; v.f = f;
    unsigned int r = v.u + 0x7fffu + ((v.u >> 16) & 1u);
    return (unsigned short)(r >> 16);
}
__device__ __forceinline__ float bf2f(unsigned short h) {
    union { unsigned int u; float f; } v; v.u = ((unsigned int)h) << 16;
    return v.f;
}

typedef __attribute__((address_space(3))) unsigned int lds_u32_t;
typedef const __attribute__((address_space(1))) unsigned int glb_u32_t;
__device__ __forceinline__ void gl_lds16(const void* g, void* l) {
    __builtin_amdgcn_global_load_lds((glb_u32_t*)g, (lds_u32_t*)l, 16, 0, 0);
}

// ---------------- cast fp32 -> bf16 (flat) ----------------
__global__ void k_cast(const float* __restrict__ in, unsigned short* __restrict__ out, int n) {
    int i = (blockIdx.x * blockDim.x + threadIdx.x) * 4;
    if (i + 3 < n) {
        float4 v = *reinterpret_cast<const float4*>(in + i);
        ushort4 o;
        o.x = f2bf(v.x); o.y = f2bf(v.y); o.z = f2bf(v.z); o.w = f2bf(v.w);
        *reinterpret_cast<ushort4*>(out + i) = o;
    }
}

// ---------------- transpose + cast: in [K][N] f32 -> out [N][K] bf16 ----------------
__global__ void k_transpose_cast(const float* __restrict__ in, unsigned short* __restrict__ out,
                                 int K, int N) {
    __shared__ float tile[32][33];
    int n0 = blockIdx.x * 32, k0 = blockIdx.y * 32;
    int tx = threadIdx.x, ty = threadIdx.y; // block (32,8)
    #pragma unroll
    for (int i = 0; i < 4; ++i)
        tile[ty + i * 8][tx] = in[(size_t)(k0 + ty + i * 8) * N + n0 + tx];
    __syncthreads();
    #pragma unroll
    for (int i = 0; i < 4; ++i)
        out[(size_t)(n0 + ty + i * 8) * K + k0 + tx] = f2bf(tile[tx][ty + i * 8]);
}

// ---------------- fill float ----------------
__global__ void k_fill(float* __restrict__ p, float v, int n) {
    int i = blockIdx.x * blockDim.x + threadIdx.x;
    if (i < n) p[i] = v;
}

// ---------------- bf16 MFMA GEMM (m97 structure): out = A[M,K] * Bt[N,K]^T + bias ----------------
// LDS tiles are unpadded [128][32] bf16 so global_load_lds's wave-uniform-base + lane*16
// destination rule lands each 16B chunk exactly at its row-major position.
// mode 0: out bf16 row-major [M,N]
// mode 1: out bf16 scattered to [B,H,T,D] (row=b*T+t, col=h*D+d), val=(acc+bias)*scale
// mode 2: out fp32 row-major [M,N]
__global__ __launch_bounds__(256) void k_gemm(
    const unsigned short* __restrict__ A, int lda,
    const unsigned short* __restrict__ Bt, int ldb,
    const float* __restrict__ bias,
    void* __restrict__ out,
    int M, int N, int K, int mode, float scale)
{
    __shared__ unsigned short As[128 * 32];
    __shared__ unsigned short Bs[128 * 32];
    int tid  = threadIdx.x;
    int lane = tid & 63, wv = tid >> 6;
    int quad = lane >> 4, l16 = lane & 15;
    int bm = blockIdx.y * 128, bn = blockIdx.x * 128;
    int wm = (wv >> 1) * 64,  wn = (wv & 1) * 64;

    f32x4 acc[4][4] = {};

    // staging geometry: element e = s*256 + tid covers row=e>>2 (0..127), col=(e&3)*8
    int srow = tid >> 2, scol = (tid & 3) * 8;

    for (int k0 = 0; k0 < K; k0 += 32) {
        #pragma unroll
        for (int s = 0; s < 2; ++s) {
            int row = s * 64 + srow;
            // wave-uniform LDS base: element (s*256 + wv*64)*8
            gl_lds16(&A[(size_t)(bm + row) * lda + k0 + scol], &As[(s * 256 + wv * 64) * 8]);
            gl_lds16(&Bt[(size_t)(bn + row) * ldb + k0 + scol], &Bs[(s * 256 + wv * 64) * 8]);
        }
        __syncthreads();
        bf16x8 af[4], bfv[4];
        #pragma unroll
        for (int mi = 0; mi < 4; ++mi)
            af[mi] = *reinterpret_cast<const bf16x8*>(&As[(wm + mi * 16 + l16) * 32 + quad * 8]);
        #pragma unroll
        for (int ni = 0; ni < 4; ++ni)
            bfv[ni] = *reinterpret_cast<const bf16x8*>(&Bs[(wn + ni * 16 + l16) * 32 + quad * 8]);
        #pragma unroll
        for (int mi = 0; mi < 4; ++mi)
            #pragma unroll
            for (int ni = 0; ni < 4; ++ni)
                acc[mi][ni] = __builtin_amdgcn_mfma_f32_16x16x32_bf16(af[mi], bfv[ni], acc[mi][ni], 0, 0, 0);
        __syncthreads();
    }

    #pragma unroll
    for (int mi = 0; mi < 4; ++mi) {
        #pragma unroll
        for (int ni = 0; ni < 4; ++ni) {
            int col = bn + wn + ni * 16 + l16;
            float bsv = bias[col];
            #pragma unroll
            for (int ri = 0; ri < 4; ++ri) {
                int row = bm + wm + mi * 16 + quad * 4 + ri;
                float val = (acc[mi][ni][ri] + bsv) * scale;
                if (mode == 0) {
                    reinterpret_cast<unsigned short*>(out)[(size_t)row * N + col] = f2bf(val);
                } else if (mode == 1) {
                    int b = row >> 12, t = row & 4095;
                    int h = col >> 6,  d = col & 63;
                    size_t idx = (((size_t)b * 16 + h) * 4096 + t) * 64 + d;
                    reinterpret_cast<unsigned short*>(out)[idx] = f2bf(val);
                } else {
                    reinterpret_cast<float*>(out)[(size_t)row * N + col] = val;
                }
            }
        }
    }
}

// ---------------- dilated attention, one branch ----------------
// grid: (8 qtiles, n_seg, B*H), block 256. eff=512, D=64.
__global__ __launch_bounds__(256) void k_attn(
    const unsigned short* __restrict__ qg,
    const unsigned short* __restrict__ kg,
    const unsigned short* __restrict__ vg,
    unsigned short* __restrict__ Obr,
    float* __restrict__ Lbr,
    int w, int r, int branch)
{
    __shared__ unsigned short Qs[64 * 72];
    __shared__ unsigned short Ks[64 * 72];
    __shared__ unsigned short Vs[64 * 72];   // transposed: [d][kcol]
    __shared__ float          Ss[64 * 68];
    __shared__ unsigned short Ps[64 * 72];
    __shared__ float m_s[64], l_s[64], alpha_s[64];

    int tid  = threadIdx.x;
    int lane = tid & 63, wv = tid >> 6;
    int quad = lane >> 4, l16 = lane & 15;
    int qt  = blockIdx.x;
    int seg = blockIdx.y;
    int bh  = blockIdx.z;
    int h   = bh & 15;
    int off = h & (r - 1);   // h % r, r power of 2
    const size_t headoff = (size_t)bh * 4096 * 64;
    const unsigned short* qh = qg + headoff;
    const unsigned short* kh = kg + headoff;
    const unsigned short* vh = vg + headoff;

    // load Q tile (64 rows x 64 d)
    #pragma unroll
    for (int s = 0; s < 2; ++s) {
        int vi  = s * 256 + tid;
        int row = vi >> 3, c8 = (vi & 7) * 8;
        int pos = seg * w + off + (qt * 64 + row) * r;
        *reinterpret_cast<uint4*>(&Qs[row * 72 + c8]) =
            *reinterpret_cast<const uint4*>(&qh[(size_t)pos * 64 + c8]);
    }
    if (tid < 64) { m_s[tid] = -1e30f; l_s[tid] = 0.f; }

    f32x4 acc[4] = {};
    int base_m = wv * 16;

    for (int jt = 0; jt <= qt; ++jt) {
        __syncthreads();  // prev-iter reads done before overwriting K/V; also covers Q/m/l init
        #pragma unroll
        for (int s = 0; s < 2; ++s) {
            int vi  = s * 256 + tid;
            int row = vi >> 3, c8 = (vi & 7) * 8;
            int pos = seg * w + off + (jt * 64 + row) * r;
            *reinterpret_cast<uint4*>(&Ks[row * 72 + c8]) =
                *reinterpret_cast<const uint4*>(&kh[(size_t)pos * 64 + c8]);
            uint4 vv = *reinterpret_cast<const uint4*>(&vh[(size_t)pos * 64 + c8]);
            const unsigned short* pv = reinterpret_cast<const unsigned short*>(&vv);
            #pragma unroll
            for (int u = 0; u < 8; ++u)
                Vs[(c8 + u) * 72 + row] = pv[u];
        }
        __syncthreads();

        // S = Q K^T, masked, into LDS
        #pragma unroll
        for (int nt = 0; nt < 4; ++nt) {
            f32x4 s4 = {};
            #pragma unroll
            for (int ks = 0; ks < 2; ++ks) {
                bf16x8 a = *reinterpret_cast<const bf16x8*>(&Qs[(base_m + l16) * 72 + ks * 32 + quad * 8]);
                bf16x8 b = *reinterpret_cast<const bf16x8*>(&Ks[(nt * 16 + l16) * 72 + ks * 32 + quad * 8]);
                s4 = __builtin_amdgcn_mfma_f32_16x16x32_bf16(a, b, s4, 0, 0, 0);
            }
            #pragma unroll
            for (int ri = 0; ri < 4; ++ri) {
                int row  = base_m + quad * 4 + ri;
                int colk = nt * 16 + l16;
                int qi = qt * 64 + row, kj = jt * 64 + colk;
                Ss[row * 68 + colk] = (kj <= qi) ? s4[ri] : -1e30f;
            }
        }
        __syncthreads();

        // online softmax: 4 threads per row, 16 cols each, shfl_xor combine
        {
            int row  = tid >> 2;       // 0..63 (4 consecutive lanes share a row)
            int part = tid & 3;
            float mx = -1e30f;
            #pragma unroll
            for (int c = 0; c < 16; ++c) mx = fmaxf(mx, Ss[row * 68 + part * 16 + c]);
            mx = fmaxf(mx, __shfl_xor(mx, 1));
            mx = fmaxf(mx, __shfl_xor(mx, 2));
            float mold = m_s[row];
            float mnew = fmaxf(mold, mx);
            float alpha = __expf(mold - mnew);
            float sum = 0.f;
            #pragma unroll
            for (int c = 0; c < 16; ++c) {
                float p = __expf(Ss[row * 68 + part * 16 + c] - mnew);
                Ps[row * 72 + part * 16 + c] = f2bf(p);
                sum += p;
            }
            sum += __shfl_xor(sum, 1);
            sum += __shfl_xor(sum, 2);
            if (part == 0) {
                l_s[row] = l_s[row] * alpha + sum;
                m_s[row] = mnew;
                alpha_s[row] = alpha;
            }
        }
        __syncthreads();

        // O = O*alpha + P V
        float al[4];
        #pragma unroll
        for (int ri = 0; ri < 4; ++ri) al[ri] = alpha_s[base_m + quad * 4 + ri];
        #pragma unroll
        for (int dt = 0; dt < 4; ++dt) {
            f32x4 a4 = acc[dt];
            #pragma unroll
            for (int ri = 0; ri < 4; ++ri) a4[ri] *= al[ri];
            #pragma unroll
            for (int ks = 0; ks < 2; ++ks) {
                bf16x8 a = *reinterpret_cast<const bf16x8*>(&Ps[(base_m + l16) * 72 + ks * 32 + quad * 8]);
                bf16x8 b = *reinterpret_cast<const bf16x8*>(&Vs[(dt * 16 + l16) * 72 + ks * 32 + quad * 8]);
                a4 = __builtin_amdgcn_mfma_f32_16x16x32_bf16(a, b, a4, 0, 0, 0);
            }
            acc[dt] = a4;
        }
    }
    __syncthreads();

    size_t obase = ((size_t)(branch * 32 + bh)) * 4096 * 64;
    #pragma unroll
    for (int dt = 0; dt < 4; ++dt) {
        #pragma unroll
        for (int ri = 0; ri < 4; ++ri) {
            int row = base_m + quad * 4 + ri;
            int pos = seg * w + off + (qt * 64 + row) * r;
            int d   = dt * 16 + l16;
            Obr[obase + (size_t)pos * 64 + d] = f2bf(acc[dt][ri] / l_s[row]);
        }
    }
    if (tid < 64) {
        int row = tid;
        int pos = seg * w + off + (qt * 64 + row) * r;
        Lbr[(size_t)(branch * 32 + bh) * 4096 + pos] = m_s[row] + __logf(l_s[row]);
    }
}

// ---------------- combine branches via LSE weights ----------------
__global__ void k_combine(const unsigned short* __restrict__ Obr,
                          const float* __restrict__ Lbr,
                          unsigned short* __restrict__ yb)
{
    int g   = blockIdx.x * blockDim.x + threadIdx.x; // 131072 rows * 8 parts
    int row = g >> 3;
    int d0  = (g & 7) * 8;
    const int R = 2 * 16 * 4096;
    float L0 = Lbr[row], L1 = Lbr[R + row], L2 = Lbr[2 * R + row];
    float m  = fmaxf(L0, fmaxf(L1, L2));
    float w0 = __expf(L0 - m), w1 = __expf(L1 - m), w2 = __expf(L2 - m);
    float inv = 1.f / (w0 + w1 + w2);
    int bh = row >> 12, t = row & 4095;
    int b = bh >> 4, h = bh & 15;
    uint4 v0 = *reinterpret_cast<const uint4*>(&Obr[(size_t)row * 64 + d0]);
    uint4 v1 = *reinterpret_cast<const uint4*>(&Obr[(size_t)R * 64 + (size_t)row * 64 + d0]);
    uint4 v2 = *reinterpret_cast<const uint4*>(&Obr[(size_t)2 * R * 64 + (size_t)row * 64 + d0]);
    const unsigned short* p0 = reinterpret_cast<const unsigned short*>(&v0);
    const unsigned short* p1 = reinterpret_cast<const unsigned short*>(&v1);
    const unsigned short* p2 = reinterpret_cast<const unsigned short*>(&v2);
    unsigned short o[8];
    #pragma unroll
    for (int u = 0; u < 8; ++u)
        o[u] = f2bf((w0 * bf2f(p0[u]) + w1 * bf2f(p1[u]) + w2 * bf2f(p2[u])) * inv);
    size_t yidx = (((size_t)b * 4096 + t) * 1024) + (size_t)h * 64 + d0;
    *reinterpret_cast<uint4*>(&yb[yidx]) = *reinterpret_cast<const uint4*>(o);
}

extern "C" void kernel_launch(void* const* d_in, const int* in_sizes, int n_in,
                              void* d_out, int out_size, void* d_ws, size_t ws_size,
                              hipStream_t stream)
{
    const float* x        = (const float*)d_in[0];
    const float* c_attn_w = (const float*)d_in[1];
    const float* c_attn_b = (const float*)d_in[2];
    const float* q_w      = (const float*)d_in[3];
    const float* q_b      = (const float*)d_in[4];
    const float* k_w      = (const float*)d_in[5];
    const float* k_b      = (const float*)d_in[6];
    const float* v_w      = (const float*)d_in[7];
    const float* v_b      = (const float*)d_in[8];
    const float* o_w      = (const float*)d_in[9];
    const float* o_b      = (const float*)d_in[10];

    char* ws = (char*)d_ws;
    size_t off = 0;
    auto alloc = [&](size_t bytes) -> char* {
        char* p = ws + off; off += (bytes + 255) & ~(size_t)255; return p;
    };
    unsigned short* xb    = (unsigned short*)alloc(8192ull * 1024 * 2);
    unsigned short* wqkvT = (unsigned short*)alloc(3072ull * 1024 * 2);
    unsigned short* wqT   = (unsigned short*)alloc(1024ull * 1024 * 2);
    unsigned short* wkT   = (unsigned short*)alloc(1024ull * 1024 * 2);
    unsigned short* wvT   = (unsigned short*)alloc(1024ull * 1024 * 2);
    unsigned short* woT   = (unsigned short*)alloc(1024ull * 1024 * 2);
    unsigned short* qkvb  = (unsigned short*)alloc(8192ull * 3072 * 2);
    unsigned short* qb    = (unsigned short*)alloc(2ull * 16 * 4096 * 64 * 2);
    unsigned short* kb    = (unsigned short*)alloc(2ull * 16 * 4096 * 64 * 2);
    unsigned short* vb    = (unsigned short*)alloc(2ull * 16 * 4096 * 64 * 2);
    unsigned short* Obr   = (unsigned short*)alloc(3ull * 2 * 16 * 4096 * 64 * 2);
    float*          Lbr   = (float*)alloc(3ull * 2 * 16 * 4096 * 4);
    unsigned short* yb    = xb;   // alias: x no longer needed after GEMM1

    // 1. cast x to bf16
    k_cast<<<(8192 * 1024) / 1024, 256, 0, stream>>>(x, xb, 8192 * 1024);
    // 2. transpose-cast weights to [N][K] bf16
    k_transpose_cast<<<dim3(3072 / 32, 1024 / 32), dim3(32, 8), 0, stream>>>(c_attn_w, wqkvT, 1024, 3072);
    k_transpose_cast<<<dim3(32, 32), dim3(32, 8), 0, stream>>>(q_w, wqT, 1024, 1024);
    k_transpose_cast<<<dim3(32, 32), dim3(32, 8), 0, stream>>>(k_w, wkT, 1024, 1024);
    k_transpose_cast<<<dim3(32, 32), dim3(32, 8), 0, stream>>>(v_w, wvT, 1024, 1024);
    k_transpose_cast<<<dim3(32, 32), dim3(32, 8), 0, stream>>>(o_w, woT, 1024, 1024);
    // 3. qkv = x @ c_attn_w + b
    k_gemm<<<dim3(24, 64), 256, 0, stream>>>(xb, 1024, wqkvT, 1024, c_attn_b, qkvb, 8192, 3072, 1024, 0, 1.f);
    // 4. q/k/v projections -> [B,H,T,D] bf16 (q scaled by D^-0.5)
    k_gemm<<<dim3(8, 64), 256, 0, stream>>>(qkvb + 0,    3072, wqT, 1024, q_b, qb, 8192, 1024, 1024, 1, 0.125f);
    k_gemm<<<dim3(8, 64), 256, 0, stream>>>(qkvb + 1024, 3072, wkT, 1024, k_b, kb, 8192, 1024, 1024, 1, 1.f);
    k_gemm<<<dim3(8, 64), 256, 0, stream>>>(qkvb + 2048, 3072, wvT, 1024, v_b, vb, 8192, 1024, 1024, 1, 1.f);
    // 5. init Lbr to -1e30 (uncovered positions must have zero combine weight)
    k_fill<<<(3 * 131072) / 256, 256, 0, stream>>>(Lbr, -1e30f, 3 * 131072);
    // 6. attention branches: (w,r) = (512,1),(1024,2),(2048,4)
    k_attn<<<dim3(8, 8, 32), 256, 0, stream>>>(qb, kb, vb, Obr, Lbr, 512, 1, 0);
    k_attn<<<dim3(8, 4, 32), 256, 0, stream>>>(qb, kb, vb, Obr, Lbr, 1024, 2, 1);
    k_attn<<<dim3(8, 2, 32), 256, 0, stream>>>(qb, kb, vb, Obr, Lbr, 2048, 4, 2);
    // 7. combine branches -> y [B,T,C] bf16
    k_combine<<<4096, 256, 0, stream>>>(Obr, Lbr, yb);
    // 8. out = y @ o_w + o_b (fp32)
    k_gemm<<<dim3(8, 64), 256, 0, stream>>>(yb, 1024, woT, 1024, o_b, d_out, 8192, 1024, 1024, 2, 1.f);
}